// Round 11
// baseline (1908.079 us; speedup 1.0000x reference)
//
#include <hip/hip_runtime.h>
#include <math.h>

#ifndef M_PI
#define M_PI 3.14159265358979323846
#endif

#define MATS 8
#define BLK 192           // k_logm: MATS*24 threads; k_expm/k_csqrt: MATS4*12
#define MATS4 16          // 12 threads/matrix, tile = 4r x 12c
#define NMATS 38400
#define NGROUPS 1536
#define LROW 588          // per-buffer stride in floats (24*24 + 12)

static_assert(BLK == MATS * 24, "block = MATS*24");
static_assert(BLK == MATS4 * 12, "block = MATS4*12");

struct Coefs { float c[32]; };

// ---------- vector helpers (all fully unrolled; no dynamic reg indexing) ----------
__device__ __forceinline__ void ld12(const float* p, float* r) {
  const float4* q = (const float4*)p;
#pragma unroll
  for (int i = 0; i < 3; ++i) {
    float4 v = q[i];
    r[4*i+0] = v.x; r[4*i+1] = v.y; r[4*i+2] = v.z; r[4*i+3] = v.w;
  }
}
__device__ __forceinline__ void st12(float* p, const float* r) {
  float4* q = (float4*)p;
#pragma unroll
  for (int i = 0; i < 3; ++i)
    q[i] = make_float4(r[4*i+0], r[4*i+1], r[4*i+2], r[4*i+3]);
}
__device__ __forceinline__ void ld24(const float* p, float* r) {
  const float4* q = (const float4*)p;
#pragma unroll
  for (int i = 0; i < 6; ++i) {
    float4 v = q[i];
    r[4*i+0] = v.x; r[4*i+1] = v.y; r[4*i+2] = v.z; r[4*i+3] = v.w;
  }
}
__device__ __forceinline__ void zero12(float* r) {
#pragma unroll
  for (int j = 0; j < 12; ++j) r[j] = 0.f;
}
// 2-row layout (k_logm): += c on diagonal elements in this thread's 2x12 tile
__device__ __forceinline__ void add_diag(float* t0, float* t1, int p, int h, float c) {
#pragma unroll
  for (int j = 0; j < 12; ++j) {
    t0[j] += (h == 0 && j == p) ? c : 0.f;
    t1[j] += (h == 1 && j == p) ? c : 0.f;
  }
}
// 4-row layout: rows r0=p, r1=p+6, r2=p+12, r3=p+18, cols c0..c0+11.
// diag (r,r) lands: h==0 -> t0[j=p], t1[j=p+6]; h==1 -> t2[j=p], t3[j=p+6].
__device__ __forceinline__ void diag4(float* t0, float* t1, float* t2, float* t3,
                                      int p, int h, float c) {
#pragma unroll
  for (int j = 0; j < 12; ++j) {
    t0[j] += (h == 0 && j == p)     ? c : 0.f;
    t1[j] += (h == 0 && j == p + 6) ? c : 0.f;
    t2[j] += (h == 1 && j == p)     ? c : 0.f;
    t3[j] += (h == 1 && j == p + 6) ? c : 0.f;
  }
}

// acc{0,1}[j] += sum_k a{0,1}[k] * B[k*24 + j]  (k_logm variant, A preloaded)
__device__ __forceinline__ void mmtile(const float* __restrict__ a0,
                                       const float* __restrict__ a1,
                                       const float* __restrict__ B,
                                       float* __restrict__ acc0,
                                       float* __restrict__ acc1) {
#pragma unroll
  for (int k = 0; k < 24; ++k) {
    float b[12];
    ld12(B + k*24, b);
    const float x0 = a0[k], x1 = a1[k];
#pragma unroll
    for (int j = 0; j < 12; ++j) { acc0[j] += x0 * b[j]; acc1[j] += x1 * b[j]; }
    if ((k % 6) == 5) __builtin_amdgcn_sched_barrier(0);
  }
}

// 4-row variant: one B read serves 4 output rows (verified round 10).
__device__ __forceinline__ void mmtile4(const float* __restrict__ rA0,
                                        const float* __restrict__ rA1,
                                        const float* __restrict__ rA2,
                                        const float* __restrict__ rA3,
                                        const float* __restrict__ B,
                                        float* __restrict__ acc0,
                                        float* __restrict__ acc1,
                                        float* __restrict__ acc2,
                                        float* __restrict__ acc3) {
#pragma unroll
  for (int half = 0; half < 2; ++half) {
    float a0[12], a1[12], a2[12], a3[12];
    ld12(rA0 + half*12, a0); ld12(rA1 + half*12, a1);
    ld12(rA2 + half*12, a2); ld12(rA3 + half*12, a3);
#pragma unroll
    for (int kk = 0; kk < 12; ++kk) {
      const int k = half*12 + kk;
      float b[12];
      ld12(B + k*24, b);
      const float x0 = a0[kk], x1 = a1[kk], x2 = a2[kk], x3 = a3[kk];
#pragma unroll
      for (int j = 0; j < 12; ++j) {
        acc0[j] += x0 * b[j]; acc1[j] += x1 * b[j];
        acc2[j] += x2 * b[j]; acc3[j] += x3 * b[j];
      }
      if ((kk % 6) == 5) __builtin_amdgcn_sched_barrier(0);
    }
  }
}

// ---------- K1: logm, degree-23 Chebyshev->monomial, PS k=4 (unchanged) ----------
__global__ __launch_bounds__(BLK) void k_logm(const float* __restrict__ x,
                                              float* __restrict__ out, Coefs cf) {
  __shared__ __align__(16) float lds[MATS][4][LROW];   // 75264 B -> 2 blocks/CU
  const int tid = threadIdx.x;
  const int lm = tid / 24, t24 = tid % 24, p = t24 >> 1, h = t24 & 1, c0 = h * 12;
  const long mat = (long)blockIdx.x * MATS + lm;
  float *L0 = lds[lm][0], *L1 = lds[lm][1], *L2 = lds[lm][2], *L3 = lds[lm][3];
  const float invd = cf.c[30], cd = cf.c[31];

  float u0[12], u1[12];
  ld12(x + mat*576 + p*24 + c0, u0);
  ld12(x + mat*576 + (p+12)*24 + c0, u1);
#pragma unroll
  for (int j = 0; j < 12; ++j) { u0[j] *= invd; u1[j] *= invd; }
  add_diag(u0, u1, p, h, -cd);
  st12(&L0[p*24 + c0], u0); st12(&L0[(p+12)*24 + c0], u1);
  __syncthreads();

  float a0[24], a1[24], t0[12], t1[12];
  // u2 -> L1
  ld24(&L0[p*24], a0); ld24(&L0[(p+12)*24], a1);
  zero12(t0); zero12(t1);
  mmtile(a0, a1, L0 + c0, t0, t1);
  st12(&L1[p*24 + c0], t0); st12(&L1[(p+12)*24 + c0], t1);
  __syncthreads();
  // u3 -> L2
  ld24(&L1[p*24], a0); ld24(&L1[(p+12)*24], a1);
  zero12(t0); zero12(t1);
  mmtile(a0, a1, L0 + c0, t0, t1);
  st12(&L2[p*24 + c0], t0); st12(&L2[(p+12)*24 + c0], t1);
  __syncthreads();
  // u4 -> (regs), then overwrite L0
  ld24(&L2[p*24], a0); ld24(&L2[(p+12)*24], a1);
  zero12(t0); zero12(t1);
  mmtile(a0, a1, L0 + c0, t0, t1);
  __syncthreads();                       // all reads of L0(=u) done
  st12(&L0[p*24 + c0], t0); st12(&L0[(p+12)*24 + c0], t1);
  __syncthreads();                       // L0 = u4 visible

  // top PS block jb=5: c20 I + c21 u + c22 u2 + c23 u3
  float P0[12], P1[12], w0[12], w1[12];
  ld12(&L1[p*24 + c0], w0); ld12(&L1[(p+12)*24 + c0], w1);
#pragma unroll
  for (int j = 0; j < 12; ++j) {
    P0[j] = cf.c[21]*u0[j] + cf.c[22]*w0[j];
    P1[j] = cf.c[21]*u1[j] + cf.c[22]*w1[j];
  }
  ld12(&L2[p*24 + c0], w0); ld12(&L2[(p+12)*24 + c0], w1);
#pragma unroll
  for (int j = 0; j < 12; ++j) { P0[j] += cf.c[23]*w0[j]; P1[j] += cf.c[23]*w1[j]; }
  add_diag(P0, P1, p, h, cf.c[20]);

#pragma unroll 1
  for (int jb = 4; jb >= 0; --jb) {
    st12(&L3[p*24 + c0], P0); st12(&L3[(p+12)*24 + c0], P1);
    __syncthreads();
    float acc0[12], acc1[12];
    ld12(&L1[p*24 + c0], w0); ld12(&L1[(p+12)*24 + c0], w1);
#pragma unroll
    for (int j = 0; j < 12; ++j) {
      acc0[j] = cf.c[4*jb+1]*u0[j] + cf.c[4*jb+2]*w0[j];
      acc1[j] = cf.c[4*jb+1]*u1[j] + cf.c[4*jb+2]*w1[j];
    }
    ld12(&L2[p*24 + c0], w0); ld12(&L2[(p+12)*24 + c0], w1);
#pragma unroll
    for (int j = 0; j < 12; ++j) { acc0[j] += cf.c[4*jb+3]*w0[j]; acc1[j] += cf.c[4*jb+3]*w1[j]; }
    add_diag(acc0, acc1, p, h, cf.c[4*jb]);
    ld24(&L3[p*24], a0); ld24(&L3[(p+12)*24], a1);
    mmtile(a0, a1, L0 + c0, acc0, acc1);   // += P * u4
#pragma unroll
    for (int j = 0; j < 12; ++j) { P0[j] = acc0[j]; P1[j] = acc1[j]; }
    __syncthreads();                       // L3 reads done before next overwrite
  }
  st12(out + mat*576 + p*24 + c0, P0);
  st12(out + mat*576 + (p+12)*24 + c0, P1);
}

// ---------- K2: graph aggregation (unchanged structure) ----------
__global__ __launch_bounds__(256) void k_agg(const float* __restrict__ A,
                                             float* __restrict__ io) {
  __shared__ __align__(16) float Lg[25*576];
  __shared__ float Ag[625];
  const int g = blockIdx.x;
  const float* Lbase = io + (long)g * 25 * 576;
  for (int i = threadIdx.x; i < 25*576/4; i += 256)
    ((float4*)Lg)[i] = ((const float4*)Lbase)[i];
  for (int i = threadIdx.x; i < 625; i += 256)
    Ag[i] = A[(long)g*625 + i];
  __syncthreads();
  for (int rr = threadIdx.x; rr < 600; rr += 256) {
    const int r = rr / 25, j = rr % 25;
    float acc[24];
#pragma unroll
    for (int q = 0; q < 24; ++q) acc[q] = 0.f;
#pragma unroll 1
    for (int v = 0; v < 25; ++v) {
      const float a = Ag[v*25 + j];
      float b[24];
      ld24(&Lg[v*576 + r*24], b);
#pragma unroll
      for (int q = 0; q < 24; ++q) acc[q] += a * b[q];
    }
    float* dst = io + ((long)g*25 + j)*576 + (long)r*24;
    float4* qd = (float4*)dst;
#pragma unroll
    for (int i = 0; i < 6; ++i)
      qd[i] = make_float4(acc[4*i], acc[4*i+1], acc[4*i+2], acc[4*i+3]);
  }
}

// ---------- K3: expm, degree-11 Chebyshev->monomial, PS k=3 ----------
// 4-row retile (clone of verified k_csqrt pattern): 12 threads/matrix,
// MATS4=16, u/u2 tiles register-resident, 2 LDS buffers. LDS-instr per
// matrix-matmul 31.5 -> 18. Per-element k-order unchanged -> FP-identical.
__global__ __launch_bounds__(BLK, 2) void k_expm(float* __restrict__ io, Coefs cf) {
  __shared__ __align__(16) float lds[MATS4][2][LROW];  // 75264 B -> 2 blocks/CU
  const int tid = threadIdx.x;
  const int lm = tid / 12, t12 = tid % 12, p = t12 >> 1, h = t12 & 1, c0 = h * 12;
  const long mat = (long)blockIdx.x * MATS4 + lm;
  float *La = lds[lm][0], *Lb = lds[lm][1];
  const int r0 = p, r1 = p + 6, r2 = p + 12, r3 = p + 18;
  const float invd = cf.c[30], cd = cf.c[31];

  float uu0[12], uu1[12], uu2[12], uu3[12];
  ld12(io + mat*576 + r0*24 + c0, uu0);
  ld12(io + mat*576 + r1*24 + c0, uu1);
  ld12(io + mat*576 + r2*24 + c0, uu2);
  ld12(io + mat*576 + r3*24 + c0, uu3);
#pragma unroll
  for (int j = 0; j < 12; ++j) {
    uu0[j] *= invd; uu1[j] *= invd; uu2[j] *= invd; uu3[j] *= invd;
  }
  diag4(uu0, uu1, uu2, uu3, p, h, -cd);
  st12(&La[r0*24 + c0], uu0); st12(&La[r1*24 + c0], uu1);
  st12(&La[r2*24 + c0], uu2); st12(&La[r3*24 + c0], uu3);
  __syncthreads();                       // La = u

  // u2 -> regs (w, persistent) + Lb (rows needed once for u3)
  float w0[12], w1[12], w2[12], w3[12];
  zero12(w0); zero12(w1); zero12(w2); zero12(w3);
  mmtile4(&La[r0*24], &La[r1*24], &La[r2*24], &La[r3*24], La + c0,
          w0, w1, w2, w3);
  st12(&Lb[r0*24 + c0], w0); st12(&Lb[r1*24 + c0], w1);
  st12(&Lb[r2*24 + c0], w2); st12(&Lb[r3*24 + c0], w3);
  __syncthreads();                       // Lb = u2

  // u3 = u2 * u -> regs
  float t0[12], t1[12], t2[12], t3[12];
  zero12(t0); zero12(t1); zero12(t2); zero12(t3);
  mmtile4(&Lb[r0*24], &Lb[r1*24], &Lb[r2*24], &Lb[r3*24], La + c0,
          t0, t1, t2, t3);
  __syncthreads();                       // all reads of La(u) + Lb(u2) done
  st12(&La[r0*24 + c0], t0); st12(&La[r1*24 + c0], t1);
  st12(&La[r2*24 + c0], t2); st12(&La[r3*24 + c0], t3);   // La = u3
  // initial P (top block): c9 I + c10 u + c11 u2 -> Lb (reuse t)
#pragma unroll
  for (int j = 0; j < 12; ++j) {
    t0[j] = cf.c[10]*uu0[j] + cf.c[11]*w0[j];
    t1[j] = cf.c[10]*uu1[j] + cf.c[11]*w1[j];
    t2[j] = cf.c[10]*uu2[j] + cf.c[11]*w2[j];
    t3[j] = cf.c[10]*uu3[j] + cf.c[11]*w3[j];
  }
  diag4(t0, t1, t2, t3, p, h, cf.c[9]);
  st12(&Lb[r0*24 + c0], t0); st12(&Lb[r1*24 + c0], t1);
  st12(&Lb[r2*24 + c0], t2); st12(&Lb[r3*24 + c0], t3);
  __syncthreads();                       // La = u3, Lb = P

#pragma unroll 1
  for (int jb = 2; jb >= 0; --jb) {
    float acc0[12], acc1[12], acc2[12], acc3[12];
#pragma unroll
    for (int j = 0; j < 12; ++j) {
      acc0[j] = cf.c[3*jb+1]*uu0[j] + cf.c[3*jb+2]*w0[j];
      acc1[j] = cf.c[3*jb+1]*uu1[j] + cf.c[3*jb+2]*w1[j];
      acc2[j] = cf.c[3*jb+1]*uu2[j] + cf.c[3*jb+2]*w2[j];
      acc3[j] = cf.c[3*jb+1]*uu3[j] + cf.c[3*jb+2]*w3[j];
    }
    diag4(acc0, acc1, acc2, acc3, p, h, cf.c[3*jb]);
    mmtile4(&Lb[r0*24], &Lb[r1*24], &Lb[r2*24], &Lb[r3*24], La + c0,
            acc0, acc1, acc2, acc3);     // += P * u3
    if (jb > 0) {
      __syncthreads();                   // Lb(P-row) reads done
      st12(&Lb[r0*24 + c0], acc0); st12(&Lb[r1*24 + c0], acc1);
      st12(&Lb[r2*24 + c0], acc2); st12(&Lb[r3*24 + c0], acc3);
      __syncthreads();                   // Lb = newP
    } else {
      st12(io + mat*576 + r0*24 + c0, acc0);
      st12(io + mat*576 + r1*24 + c0, acc1);
      st12(io + mat*576 + r2*24 + c0, acc2);
      st12(io + mat*576 + r3*24 + c0, acc3);
    }
  }
}

// ---------- K4: congruence + Frobenius norm + 9-step Newton-Schulz sqrt ----------
// Round-10 4-row structure + register-carry of M/Y tiles: the update phases
// combine from Mr/Yr registers instead of re-reading own tiles from LDS
// (removes ~96 ld12/thread; values bit-identical). Peak live regs ~210 of 256.
__global__ __launch_bounds__(BLK, 2) void k_csqrt(float* __restrict__ io,
                                                  const float* __restrict__ W) {
  __shared__ __align__(16) float lds[MATS4][2][LROW];  // 75264 B
  __shared__ __align__(16) float Wt[576];
  __shared__ float red[BLK];
  const int tid = threadIdx.x;
  const int lm = tid / 12, t12 = tid % 12, p = t12 >> 1, h = t12 & 1, c0 = h * 12;
  const long mat = (long)blockIdx.x * MATS4 + lm;
  float *La = lds[lm][0], *Lb = lds[lm][1];
  const int r0 = p, r1 = p + 6, r2 = p + 12, r3 = p + 18;

  for (int i = tid; i < 576; i += BLK) {
    const int k = i / 24, j = i % 24;
    Wt[i] = W[j*24 + k];
  }
  {
    float e[12];
    ld12(io + mat*576 + r0*24 + c0, e); st12(&La[r0*24 + c0], e);
    ld12(io + mat*576 + r1*24 + c0, e); st12(&La[r1*24 + c0], e);
    ld12(io + mat*576 + r2*24 + c0, e); st12(&La[r2*24 + c0], e);
    ld12(io + mat*576 + r3*24 + c0, e); st12(&La[r3*24 + c0], e);
  }
  __syncthreads();                                // La = E, Wt ready

  float Mr0[12], Mr1[12], Mr2[12], Mr3[12];
  {
    float t0[12], t1[12], t2[12], t3[12];
    zero12(t0); zero12(t1); zero12(t2); zero12(t3);
    mmtile4(W + r0*24, W + r1*24, W + r2*24, W + r3*24, La + c0,
            t0, t1, t2, t3);                      // F = W * E
    st12(&Lb[r0*24 + c0], t0); st12(&Lb[r1*24 + c0], t1);
    st12(&Lb[r2*24 + c0], t2); st12(&Lb[r3*24 + c0], t3);
    __syncthreads();                              // Lb = F; La(E) reads done

    zero12(t0); zero12(t1); zero12(t2); zero12(t3);
    mmtile4(&Lb[r0*24], &Lb[r1*24], &Lb[r2*24], &Lb[r3*24], Wt + c0,
            t0, t1, t2, t3);                      // C = F * W^T
    float s = 0.f;
#pragma unroll
    for (int j = 0; j < 12; ++j)
      s += t0[j]*t0[j] + t1[j]*t1[j] + t2[j]*t2[j] + t3[j]*t3[j];
    red[tid] = s;
    __syncthreads();                              // red ready; Lb(F-row) reads done
    float tot = 0.f;
#pragma unroll
    for (int q = 0; q < 12; ++q) tot += red[lm*12 + q];
    const float inv = 1.0f / sqrtf(tot);
#pragma unroll
    for (int j = 0; j < 12; ++j) {
      Mr0[j] = t0[j]*inv; Mr1[j] = t1[j]*inv;
      Mr2[j] = t2[j]*inv; Mr3[j] = t3[j]*inv;
    }
    st12(&La[r0*24 + c0], Mr0); st12(&La[r1*24 + c0], Mr1);
    st12(&La[r2*24 + c0], Mr2); st12(&La[r3*24 + c0], Mr3);
  }
  __syncthreads();                                // La = M0 (normalized)

  float Yr0[12], Yr1[12], Yr2[12], Yr3[12];
  // ---- iter 0 (a=2, Y=M): newY(=MT) = 2M - M*M ; newM = 2*MT - MT*M
  {
    float m0[12], m1[12], m2[12], m3[12];
    zero12(m0); zero12(m1); zero12(m2); zero12(m3);
    mmtile4(&La[r0*24], &La[r1*24], &La[r2*24], &La[r3*24], La + c0,
            m0, m1, m2, m3);                      // M*M
#pragma unroll
    for (int j = 0; j < 12; ++j) {
      m0[j] = 2.f*Mr0[j] - m0[j];                 // MT (= newY), from regs
      m1[j] = 2.f*Mr1[j] - m1[j];
      m2[j] = 2.f*Mr2[j] - m2[j];
      m3[j] = 2.f*Mr3[j] - m3[j];
    }
    st12(&Lb[r0*24 + c0], m0); st12(&Lb[r1*24 + c0], m1);
    st12(&Lb[r2*24 + c0], m2); st12(&Lb[r3*24 + c0], m3);  // Lb = MT
    __syncthreads();
    float q0[12], q1[12], q2[12], q3[12];
    zero12(q0); zero12(q1); zero12(q2); zero12(q3);
    mmtile4(&Lb[r0*24], &Lb[r1*24], &Lb[r2*24], &Lb[r3*24], La + c0,
            q0, q1, q2, q3);                      // MT*M
#pragma unroll
    for (int j = 0; j < 12; ++j) {
      Mr0[j] = 2.f*m0[j] - q0[j];                 // newM, MT from regs
      Mr1[j] = 2.f*m1[j] - q1[j];
      Mr2[j] = 2.f*m2[j] - q2[j];
      Mr3[j] = 2.f*m3[j] - q3[j];
      Yr0[j] = m0[j]; Yr1[j] = m1[j]; Yr2[j] = m2[j]; Yr3[j] = m3[j];
    }
    __syncthreads();                              // La(M0)/Lb(MT) reads done
    st12(&La[r0*24 + c0], Mr0); st12(&La[r1*24 + c0], Mr1);
    st12(&La[r2*24 + c0], Mr2); st12(&La[r3*24 + c0], Mr3);
    __syncthreads();                              // La = newM; Lb = Y
  }

  // ---- iters 1..7: {mm, MT-combine, ym, Y-combine, store MT, q, store Y/M}
#pragma unroll 1
  for (int it = 1; it < 8; ++it) {
    const float aa = (it < 6) ? 2.0f : 1.5f;
    const float am1 = aa - 1.0f;
    // MT = aa*M - am1*(M*M)   (M-tile from regs)
    float m0[12], m1[12], m2[12], m3[12];
    zero12(m0); zero12(m1); zero12(m2); zero12(m3);
    mmtile4(&La[r0*24], &La[r1*24], &La[r2*24], &La[r3*24], La + c0,
            m0, m1, m2, m3);
#pragma unroll
    for (int j = 0; j < 12; ++j) {
      m0[j] = aa*Mr0[j] - am1*m0[j];
      m1[j] = aa*Mr1[j] - am1*m1[j];
      m2[j] = aa*Mr2[j] - am1*m2[j];
      m3[j] = aa*Mr3[j] - am1*m3[j];
    }
    // newY = aa*Y - am1*(Y*M)  (Y-tile from regs)
    float y0[12], y1[12], y2[12], y3[12];
    zero12(y0); zero12(y1); zero12(y2); zero12(y3);
    mmtile4(&Lb[r0*24], &Lb[r1*24], &Lb[r2*24], &Lb[r3*24], La + c0,
            y0, y1, y2, y3);
#pragma unroll
    for (int j = 0; j < 12; ++j) {
      y0[j] = aa*Yr0[j] - am1*y0[j];
      y1[j] = aa*Yr1[j] - am1*y1[j];
      y2[j] = aa*Yr2[j] - am1*y2[j];
      y3[j] = aa*Yr3[j] - am1*y3[j];
    }
    __syncthreads();                              // La(M)/Lb(Y) reads done
    st12(&Lb[r0*24 + c0], m0); st12(&Lb[r1*24 + c0], m1);
    st12(&Lb[r2*24 + c0], m2); st12(&Lb[r3*24 + c0], m3);  // Lb = MT
    __syncthreads();
    // newM = aa*MT - am1*(MT*M)  (MT-tile from regs)
    float q0[12], q1[12], q2[12], q3[12];
    zero12(q0); zero12(q1); zero12(q2); zero12(q3);
    mmtile4(&Lb[r0*24], &Lb[r1*24], &Lb[r2*24], &Lb[r3*24], La + c0,
            q0, q1, q2, q3);
#pragma unroll
    for (int j = 0; j < 12; ++j) {
      Mr0[j] = aa*m0[j] - am1*q0[j];
      Mr1[j] = aa*m1[j] - am1*q1[j];
      Mr2[j] = aa*m2[j] - am1*q2[j];
      Mr3[j] = aa*m3[j] - am1*q3[j];
      Yr0[j] = y0[j]; Yr1[j] = y1[j]; Yr2[j] = y2[j]; Yr3[j] = y3[j];
    }
    __syncthreads();                              // Lb(MT)/La(M) reads done
    st12(&Lb[r0*24 + c0], Yr0); st12(&Lb[r1*24 + c0], Yr1);
    st12(&Lb[r2*24 + c0], Yr2); st12(&Lb[r3*24 + c0], Yr3); // Lb = newY
    st12(&La[r0*24 + c0], Mr0); st12(&La[r1*24 + c0], Mr1);
    st12(&La[r2*24 + c0], Mr2); st12(&La[r3*24 + c0], Mr3); // La = newM
    __syncthreads();
  }

  // ---- iter 8 (a=1.5): final Y = 1.5*Y - 0.5*(Y*M)   (Y-tile from regs)
  {
    float y0[12], y1[12], y2[12], y3[12];
    zero12(y0); zero12(y1); zero12(y2); zero12(y3);
    mmtile4(&Lb[r0*24], &Lb[r1*24], &Lb[r2*24], &Lb[r3*24], La + c0,
            y0, y1, y2, y3);
#pragma unroll
    for (int j = 0; j < 12; ++j) {
      y0[j] = 1.5f*Yr0[j] - 0.5f*y0[j];
      y1[j] = 1.5f*Yr1[j] - 0.5f*y1[j];
      y2[j] = 1.5f*Yr2[j] - 0.5f*y2[j];
      y3[j] = 1.5f*Yr3[j] - 0.5f*y3[j];
    }
    st12(io + mat*576 + r0*24 + c0, y0);
    st12(io + mat*576 + r1*24 + c0, y1);
    st12(io + mat*576 + r2*24 + c0, y2);
    st12(io + mat*576 + r3*24 + c0, y3);
  }
}

// ---------- host: Chebyshev interpolation -> monomial coefficients in u ----------
static void chebfit_host(double lo, double hi, int D, int islog, float* out) {
  const int N = 200;
  double a[32];
  for (int k = 0; k < 32; ++k) a[k] = 0.0;
  for (int i = 0; i < N; ++i) {
    double th = M_PI * (i + 0.5) / N;
    double u = cos(th);
    double xx = 0.5 * ((hi - lo) * u + (hi + lo));
    double f = islog ? log(xx) : exp(xx);
    for (int k = 0; k <= D; ++k) a[k] += f * cos(k * th);
  }
  for (int k = 0; k <= D; ++k) a[k] *= 2.0 / N;
  a[0] *= 0.5;
  double b[32], tp[32], tc[32], tn[32];
  for (int m = 0; m < 32; ++m) { b[m] = 0; tp[m] = 0; tc[m] = 0; tn[m] = 0; }
  tp[0] = 1.0; b[0] += a[0];
  tc[1] = 1.0; if (D >= 1) b[1] += a[1];
  for (int k = 2; k <= D; ++k) {
    for (int m = 0; m < 32; ++m) tn[m] = -tp[m];
    for (int m = 1; m < 32; ++m) tn[m] += 2.0 * tc[m-1];
    for (int m = 0; m <= k; ++m) b[m] += a[k] * tn[m];
    for (int m = 0; m < 32; ++m) { tp[m] = tc[m]; tc[m] = tn[m]; }
  }
  for (int m = 0; m < 32; ++m) out[m] = (float)b[m];
  out[30] = (float)(2.0 / (hi - lo));          // 1/d
  out[31] = (float)((hi + lo) / (hi - lo));    // c/d
}

extern "C" void kernel_launch(void* const* d_in, const int* in_sizes, int n_in,
                              void* d_out, int out_size, void* d_ws, size_t ws_size,
                              hipStream_t stream) {
  const float* x = (const float*)d_in[0];
  const float* A = (const float*)d_in[1];
  const float* W = (const float*)d_in[2];
  float* out = (float*)d_out;

  Coefs cl, ce;
  chebfit_host(0.47, 7.9, 23, 1, cl.c);   // log on the SPD input spectrum
  chebfit_host(-1.8, 3.9, 11, 0, ce.c);   // exp on the aggregated tangent spectrum

  k_logm <<<NMATS/MATS, BLK, 0, stream>>>(x, out, cl);
  k_agg  <<<NGROUPS,   256, 0, stream>>>(A, out);
  k_expm <<<NMATS/MATS4, BLK, 0, stream>>>(out, ce);
  k_csqrt<<<NMATS/MATS4, BLK, 0, stream>>>(out, W);
}

// Round 12
// 1179.786 us; speedup vs baseline: 1.6173x; 1.6173x over previous
//
#include <hip/hip_runtime.h>
#include <math.h>

#ifndef M_PI
#define M_PI 3.14159265358979323846
#endif

#define MATS 8
#define BLK 192           // k_logm/k_expm: MATS*24 threads; k_csqrt: MATS4*12
#define MATS4 16          // k_csqrt: 12 threads/matrix, tile = 4r x 12c
#define NMATS 38400
#define NGROUPS 1536
#define LROW 588          // per-buffer stride in floats (24*24 + 12)

static_assert(BLK == MATS * 24, "block = MATS*24");
static_assert(BLK == MATS4 * 12, "block = MATS4*12");

struct Coefs { float c[32]; };

// ---------- vector helpers (all fully unrolled; no dynamic reg indexing) ----------
__device__ __forceinline__ void ld12(const float* p, float* r) {
  const float4* q = (const float4*)p;
#pragma unroll
  for (int i = 0; i < 3; ++i) {
    float4 v = q[i];
    r[4*i+0] = v.x; r[4*i+1] = v.y; r[4*i+2] = v.z; r[4*i+3] = v.w;
  }
}
__device__ __forceinline__ void st12(float* p, const float* r) {
  float4* q = (float4*)p;
#pragma unroll
  for (int i = 0; i < 3; ++i)
    q[i] = make_float4(r[4*i+0], r[4*i+1], r[4*i+2], r[4*i+3]);
}
__device__ __forceinline__ void ld24(const float* p, float* r) {
  const float4* q = (const float4*)p;
#pragma unroll
  for (int i = 0; i < 6; ++i) {
    float4 v = q[i];
    r[4*i+0] = v.x; r[4*i+1] = v.y; r[4*i+2] = v.z; r[4*i+3] = v.w;
  }
}
__device__ __forceinline__ void zero12(float* r) {
#pragma unroll
  for (int j = 0; j < 12; ++j) r[j] = 0.f;
}
// 2-row layout: += c on diagonal elements in this thread's 2x12 tile
__device__ __forceinline__ void add_diag(float* t0, float* t1, int p, int h, float c) {
#pragma unroll
  for (int j = 0; j < 12; ++j) {
    t0[j] += (h == 0 && j == p) ? c : 0.f;
    t1[j] += (h == 1 && j == p) ? c : 0.f;
  }
}

// acc{0,1}[j] += sum_k a{0,1}[k] * B[k*24 + j]  (k_logm variant, A preloaded)
__device__ __forceinline__ void mmtile(const float* __restrict__ a0,
                                       const float* __restrict__ a1,
                                       const float* __restrict__ B,
                                       float* __restrict__ acc0,
                                       float* __restrict__ acc1) {
#pragma unroll
  for (int k = 0; k < 24; ++k) {
    float b[12];
    ld12(B + k*24, b);
    const float x0 = a0[k], x1 = a1[k];
#pragma unroll
    for (int j = 0; j < 12; ++j) { acc0[j] += x0 * b[j]; acc1[j] += x1 * b[j]; }
    if ((k % 6) == 5) __builtin_amdgcn_sched_barrier(0);
  }
}

// Register-lean 2-row variant (k_expm): A rows loaded in 12-float halves.
__device__ __forceinline__ void mmtileH(const float* __restrict__ rA0,
                                        const float* __restrict__ rA1,
                                        const float* __restrict__ B,
                                        float* __restrict__ acc0,
                                        float* __restrict__ acc1) {
#pragma unroll
  for (int half = 0; half < 2; ++half) {
    float a0[12], a1[12];
    ld12(rA0 + half*12, a0);
    ld12(rA1 + half*12, a1);
#pragma unroll
    for (int kk = 0; kk < 12; ++kk) {
      const int k = half*12 + kk;
      float b[12];
      ld12(B + k*24, b);
      const float x0 = a0[kk], x1 = a1[kk];
#pragma unroll
      for (int j = 0; j < 12; ++j) { acc0[j] += x0 * b[j]; acc1[j] += x1 * b[j]; }
      if ((kk % 6) == 5) __builtin_amdgcn_sched_barrier(0);
    }
  }
}

// 4-row variant (k_csqrt): one B read serves 4 output rows (verified round 10).
__device__ __forceinline__ void mmtile4(const float* __restrict__ rA0,
                                        const float* __restrict__ rA1,
                                        const float* __restrict__ rA2,
                                        const float* __restrict__ rA3,
                                        const float* __restrict__ B,
                                        float* __restrict__ acc0,
                                        float* __restrict__ acc1,
                                        float* __restrict__ acc2,
                                        float* __restrict__ acc3) {
#pragma unroll
  for (int half = 0; half < 2; ++half) {
    float a0[12], a1[12], a2[12], a3[12];
    ld12(rA0 + half*12, a0); ld12(rA1 + half*12, a1);
    ld12(rA2 + half*12, a2); ld12(rA3 + half*12, a3);
#pragma unroll
    for (int kk = 0; kk < 12; ++kk) {
      const int k = half*12 + kk;
      float b[12];
      ld12(B + k*24, b);
      const float x0 = a0[kk], x1 = a1[kk], x2 = a2[kk], x3 = a3[kk];
#pragma unroll
      for (int j = 0; j < 12; ++j) {
        acc0[j] += x0 * b[j]; acc1[j] += x1 * b[j];
        acc2[j] += x2 * b[j]; acc3[j] += x3 * b[j];
      }
      if ((kk % 6) == 5) __builtin_amdgcn_sched_barrier(0);
    }
  }
}

// ---------- K1: logm, degree-23 Chebyshev->monomial, PS k=4 (unchanged) ----------
__global__ __launch_bounds__(BLK) void k_logm(const float* __restrict__ x,
                                              float* __restrict__ out, Coefs cf) {
  __shared__ __align__(16) float lds[MATS][4][LROW];   // 75264 B -> 2 blocks/CU
  const int tid = threadIdx.x;
  const int lm = tid / 24, t24 = tid % 24, p = t24 >> 1, h = t24 & 1, c0 = h * 12;
  const long mat = (long)blockIdx.x * MATS + lm;
  float *L0 = lds[lm][0], *L1 = lds[lm][1], *L2 = lds[lm][2], *L3 = lds[lm][3];
  const float invd = cf.c[30], cd = cf.c[31];

  float u0[12], u1[12];
  ld12(x + mat*576 + p*24 + c0, u0);
  ld12(x + mat*576 + (p+12)*24 + c0, u1);
#pragma unroll
  for (int j = 0; j < 12; ++j) { u0[j] *= invd; u1[j] *= invd; }
  add_diag(u0, u1, p, h, -cd);
  st12(&L0[p*24 + c0], u0); st12(&L0[(p+12)*24 + c0], u1);
  __syncthreads();

  float a0[24], a1[24], t0[12], t1[12];
  // u2 -> L1
  ld24(&L0[p*24], a0); ld24(&L0[(p+12)*24], a1);
  zero12(t0); zero12(t1);
  mmtile(a0, a1, L0 + c0, t0, t1);
  st12(&L1[p*24 + c0], t0); st12(&L1[(p+12)*24 + c0], t1);
  __syncthreads();
  // u3 -> L2
  ld24(&L1[p*24], a0); ld24(&L1[(p+12)*24], a1);
  zero12(t0); zero12(t1);
  mmtile(a0, a1, L0 + c0, t0, t1);
  st12(&L2[p*24 + c0], t0); st12(&L2[(p+12)*24 + c0], t1);
  __syncthreads();
  // u4 -> (regs), then overwrite L0
  ld24(&L2[p*24], a0); ld24(&L2[(p+12)*24], a1);
  zero12(t0); zero12(t1);
  mmtile(a0, a1, L0 + c0, t0, t1);
  __syncthreads();                       // all reads of L0(=u) done
  st12(&L0[p*24 + c0], t0); st12(&L0[(p+12)*24 + c0], t1);
  __syncthreads();                       // L0 = u4 visible

  // top PS block jb=5: c20 I + c21 u + c22 u2 + c23 u3
  float P0[12], P1[12], w0[12], w1[12];
  ld12(&L1[p*24 + c0], w0); ld12(&L1[(p+12)*24 + c0], w1);
#pragma unroll
  for (int j = 0; j < 12; ++j) {
    P0[j] = cf.c[21]*u0[j] + cf.c[22]*w0[j];
    P1[j] = cf.c[21]*u1[j] + cf.c[22]*w1[j];
  }
  ld12(&L2[p*24 + c0], w0); ld12(&L2[(p+12)*24 + c0], w1);
#pragma unroll
  for (int j = 0; j < 12; ++j) { P0[j] += cf.c[23]*w0[j]; P1[j] += cf.c[23]*w1[j]; }
  add_diag(P0, P1, p, h, cf.c[20]);

#pragma unroll 1
  for (int jb = 4; jb >= 0; --jb) {
    st12(&L3[p*24 + c0], P0); st12(&L3[(p+12)*24 + c0], P1);
    __syncthreads();
    float acc0[12], acc1[12];
    ld12(&L1[p*24 + c0], w0); ld12(&L1[(p+12)*24 + c0], w1);
#pragma unroll
    for (int j = 0; j < 12; ++j) {
      acc0[j] = cf.c[4*jb+1]*u0[j] + cf.c[4*jb+2]*w0[j];
      acc1[j] = cf.c[4*jb+1]*u1[j] + cf.c[4*jb+2]*w1[j];
    }
    ld12(&L2[p*24 + c0], w0); ld12(&L2[(p+12)*24 + c0], w1);
#pragma unroll
    for (int j = 0; j < 12; ++j) { acc0[j] += cf.c[4*jb+3]*w0[j]; acc1[j] += cf.c[4*jb+3]*w1[j]; }
    add_diag(acc0, acc1, p, h, cf.c[4*jb]);
    ld24(&L3[p*24], a0); ld24(&L3[(p+12)*24], a1);
    mmtile(a0, a1, L0 + c0, acc0, acc1);   // += P * u4
#pragma unroll
    for (int j = 0; j < 12; ++j) { P0[j] = acc0[j]; P1[j] = acc1[j]; }
    __syncthreads();                       // L3 reads done before next overwrite
  }
  st12(out + mat*576 + p*24 + c0, P0);
  st12(out + mat*576 + (p+12)*24 + c0, P1);
}

// ---------- K2: graph aggregation (unchanged structure) ----------
__global__ __launch_bounds__(256) void k_agg(const float* __restrict__ A,
                                             float* __restrict__ io) {
  __shared__ __align__(16) float Lg[25*576];
  __shared__ float Ag[625];
  const int g = blockIdx.x;
  const float* Lbase = io + (long)g * 25 * 576;
  for (int i = threadIdx.x; i < 25*576/4; i += 256)
    ((float4*)Lg)[i] = ((const float4*)Lbase)[i];
  for (int i = threadIdx.x; i < 625; i += 256)
    Ag[i] = A[(long)g*625 + i];
  __syncthreads();
  for (int rr = threadIdx.x; rr < 600; rr += 256) {
    const int r = rr / 25, j = rr % 25;
    float acc[24];
#pragma unroll
    for (int q = 0; q < 24; ++q) acc[q] = 0.f;
#pragma unroll 1
    for (int v = 0; v < 25; ++v) {
      const float a = Ag[v*25 + j];
      float b[24];
      ld24(&Lg[v*576 + r*24], b);
#pragma unroll
      for (int q = 0; q < 24; ++q) acc[q] += a * b[q];
    }
    float* dst = io + ((long)g*25 + j)*576 + (long)r*24;
    float4* qd = (float4*)dst;
#pragma unroll
    for (int i = 0; i < 6; ++i)
      qd[i] = make_float4(acc[4*i], acc[4*i+1], acc[4*i+2], acc[4*i+3]);
  }
}

// ---------- K3: expm, degree-11 Chebyshev->monomial, PS k=3 (round-7, verified) ----------
__global__ __launch_bounds__(BLK, 4) void k_expm(float* __restrict__ io, Coefs cf) {
  __shared__ __align__(16) float lds[MATS][2][LROW];   // 37632 B
  const int tid = threadIdx.x;
  const int lm = tid / 24, t24 = tid % 24, p = t24 >> 1, h = t24 & 1, c0 = h * 12;
  const long mat = (long)blockIdx.x * MATS + lm;
  float *La = lds[lm][0], *Lb = lds[lm][1];
  const float invd = cf.c[30], cd = cf.c[31];

  float u0[12], u1[12];
  ld12(io + mat*576 + p*24 + c0, u0);
  ld12(io + mat*576 + (p+12)*24 + c0, u1);
#pragma unroll
  for (int j = 0; j < 12; ++j) { u0[j] *= invd; u1[j] *= invd; }
  add_diag(u0, u1, p, h, -cd);
  st12(&La[p*24 + c0], u0); st12(&La[(p+12)*24 + c0], u1);
  __syncthreads();                       // La = u

  float t0[12], t1[12];
  // u2 tiles -> regs (w) and -> Lb (rows needed once for u3)
  zero12(t0); zero12(t1);
  mmtileH(&La[p*24], &La[(p+12)*24], La + c0, t0, t1);
  float w0[12], w1[12];
#pragma unroll
  for (int j = 0; j < 12; ++j) { w0[j] = t0[j]; w1[j] = t1[j]; }   // u2 tiles (persistent)
  st12(&Lb[p*24 + c0], t0); st12(&Lb[(p+12)*24 + c0], t1);
  __syncthreads();                       // Lb = u2
  // u3 = u2 * u -> regs, overwrite La
  zero12(t0); zero12(t1);
  mmtileH(&Lb[p*24], &Lb[(p+12)*24], La + c0, t0, t1);
  __syncthreads();                       // all reads of La(u) + Lb(u2) done
  st12(&La[p*24 + c0], t0); st12(&La[(p+12)*24 + c0], t1);
  __syncthreads();                       // La = u3; Lb free

  // initial P (jb=3 top block): c9 I + c10 u + c11 u2 -> Lb
#pragma unroll
  for (int j = 0; j < 12; ++j) {
    t0[j] = cf.c[10]*u0[j] + cf.c[11]*w0[j];
    t1[j] = cf.c[10]*u1[j] + cf.c[11]*w1[j];
  }
  add_diag(t0, t1, p, h, cf.c[9]);
  st12(&Lb[p*24 + c0], t0); st12(&Lb[(p+12)*24 + c0], t1);
  __syncthreads();                       // Lb = P

#pragma unroll 1
  for (int jb = 2; jb >= 0; --jb) {
    float acc0[12], acc1[12];
#pragma unroll
    for (int j = 0; j < 12; ++j) {
      acc0[j] = cf.c[3*jb+1]*u0[j] + cf.c[3*jb+2]*w0[j];
      acc1[j] = cf.c[3*jb+1]*u1[j] + cf.c[3*jb+2]*w1[j];
    }
    add_diag(acc0, acc1, p, h, cf.c[3*jb]);
    mmtileH(&Lb[p*24], &Lb[(p+12)*24], La + c0, acc0, acc1);   // += P * u3
    if (jb > 0) {
      __syncthreads();                   // Lb(P-row) reads done
      st12(&Lb[p*24 + c0], acc0); st12(&Lb[(p+12)*24 + c0], acc1);
      __syncthreads();                   // Lb = newP
    } else {
      st12(io + mat*576 + p*24 + c0, acc0);
      st12(io + mat*576 + (p+12)*24 + c0, acc1);
    }
  }
}

// ---------- K4: congruence + Frobenius norm + 9-step Newton-Schulz sqrt ----------
// Round-11 structure (4-row + register-carry of M/Y tiles; arithmetic verified
// correct at round 11) with the allocation fix: amdgpu_waves_per_eu(1,2) caps
// the allocator's occupancy target at 2 waves/EU (LDS already limits us to
// 1.5), so the ~200-reg natural pressure fits in the 256-reg budget without
// spilling. Round 11's __launch_bounds__(BLK,2) set only a MINIMUM, and the
// allocator spilled to reach 4 waves/EU (VGPR pinned at 128, 5.4 GB scratch).
__global__ __launch_bounds__(BLK)
__attribute__((amdgpu_waves_per_eu(1, 2)))
void k_csqrt(float* __restrict__ io, const float* __restrict__ W) {
  __shared__ __align__(16) float lds[MATS4][2][LROW];  // 75264 B
  __shared__ __align__(16) float Wt[576];
  __shared__ float red[BLK];
  const int tid = threadIdx.x;
  const int lm = tid / 12, t12 = tid % 12, p = t12 >> 1, h = t12 & 1, c0 = h * 12;
  const long mat = (long)blockIdx.x * MATS4 + lm;
  float *La = lds[lm][0], *Lb = lds[lm][1];
  const int r0 = p, r1 = p + 6, r2 = p + 12, r3 = p + 18;

  for (int i = tid; i < 576; i += BLK) {
    const int k = i / 24, j = i % 24;
    Wt[i] = W[j*24 + k];
  }
  {
    float e[12];
    ld12(io + mat*576 + r0*24 + c0, e); st12(&La[r0*24 + c0], e);
    ld12(io + mat*576 + r1*24 + c0, e); st12(&La[r1*24 + c0], e);
    ld12(io + mat*576 + r2*24 + c0, e); st12(&La[r2*24 + c0], e);
    ld12(io + mat*576 + r3*24 + c0, e); st12(&La[r3*24 + c0], e);
  }
  __syncthreads();                                // La = E, Wt ready

  float Mr0[12], Mr1[12], Mr2[12], Mr3[12];
  {
    float t0[12], t1[12], t2[12], t3[12];
    zero12(t0); zero12(t1); zero12(t2); zero12(t3);
    mmtile4(W + r0*24, W + r1*24, W + r2*24, W + r3*24, La + c0,
            t0, t1, t2, t3);                      // F = W * E
    st12(&Lb[r0*24 + c0], t0); st12(&Lb[r1*24 + c0], t1);
    st12(&Lb[r2*24 + c0], t2); st12(&Lb[r3*24 + c0], t3);
    __syncthreads();                              // Lb = F; La(E) reads done

    zero12(t0); zero12(t1); zero12(t2); zero12(t3);
    mmtile4(&Lb[r0*24], &Lb[r1*24], &Lb[r2*24], &Lb[r3*24], Wt + c0,
            t0, t1, t2, t3);                      // C = F * W^T
    float s = 0.f;
#pragma unroll
    for (int j = 0; j < 12; ++j)
      s += t0[j]*t0[j] + t1[j]*t1[j] + t2[j]*t2[j] + t3[j]*t3[j];
    red[tid] = s;
    __syncthreads();                              // red ready; Lb(F-row) reads done
    float tot = 0.f;
#pragma unroll
    for (int q = 0; q < 12; ++q) tot += red[lm*12 + q];
    const float inv = 1.0f / sqrtf(tot);
#pragma unroll
    for (int j = 0; j < 12; ++j) {
      Mr0[j] = t0[j]*inv; Mr1[j] = t1[j]*inv;
      Mr2[j] = t2[j]*inv; Mr3[j] = t3[j]*inv;
    }
    st12(&La[r0*24 + c0], Mr0); st12(&La[r1*24 + c0], Mr1);
    st12(&La[r2*24 + c0], Mr2); st12(&La[r3*24 + c0], Mr3);
  }
  __syncthreads();                                // La = M0 (normalized)

  float Yr0[12], Yr1[12], Yr2[12], Yr3[12];
  // ---- iter 0 (a=2, Y=M): newY(=MT) = 2M - M*M ; newM = 2*MT - MT*M
  {
    float m0[12], m1[12], m2[12], m3[12];
    zero12(m0); zero12(m1); zero12(m2); zero12(m3);
    mmtile4(&La[r0*24], &La[r1*24], &La[r2*24], &La[r3*24], La + c0,
            m0, m1, m2, m3);                      // M*M
#pragma unroll
    for (int j = 0; j < 12; ++j) {
      m0[j] = 2.f*Mr0[j] - m0[j];                 // MT (= newY), from regs
      m1[j] = 2.f*Mr1[j] - m1[j];
      m2[j] = 2.f*Mr2[j] - m2[j];
      m3[j] = 2.f*Mr3[j] - m3[j];
    }
    st12(&Lb[r0*24 + c0], m0); st12(&Lb[r1*24 + c0], m1);
    st12(&Lb[r2*24 + c0], m2); st12(&Lb[r3*24 + c0], m3);  // Lb = MT
    __syncthreads();
    float q0[12], q1[12], q2[12], q3[12];
    zero12(q0); zero12(q1); zero12(q2); zero12(q3);
    mmtile4(&Lb[r0*24], &Lb[r1*24], &Lb[r2*24], &Lb[r3*24], La + c0,
            q0, q1, q2, q3);                      // MT*M
#pragma unroll
    for (int j = 0; j < 12; ++j) {
      Mr0[j] = 2.f*m0[j] - q0[j];                 // newM, MT from regs
      Mr1[j] = 2.f*m1[j] - q1[j];
      Mr2[j] = 2.f*m2[j] - q2[j];
      Mr3[j] = 2.f*m3[j] - q3[j];
      Yr0[j] = m0[j]; Yr1[j] = m1[j]; Yr2[j] = m2[j]; Yr3[j] = m3[j];
    }
    __syncthreads();                              // La(M0)/Lb(MT) reads done
    st12(&La[r0*24 + c0], Mr0); st12(&La[r1*24 + c0], Mr1);
    st12(&La[r2*24 + c0], Mr2); st12(&La[r3*24 + c0], Mr3);
    __syncthreads();                              // La = newM; Lb = Y
  }

  // ---- iters 1..7: {mm, MT-combine, ym, Y-combine, store MT, q, store Y/M}
#pragma unroll 1
  for (int it = 1; it < 8; ++it) {
    const float aa = (it < 6) ? 2.0f : 1.5f;
    const float am1 = aa - 1.0f;
    // MT = aa*M - am1*(M*M)   (M-tile from regs)
    float m0[12], m1[12], m2[12], m3[12];
    zero12(m0); zero12(m1); zero12(m2); zero12(m3);
    mmtile4(&La[r0*24], &La[r1*24], &La[r2*24], &La[r3*24], La + c0,
            m0, m1, m2, m3);
#pragma unroll
    for (int j = 0; j < 12; ++j) {
      m0[j] = aa*Mr0[j] - am1*m0[j];
      m1[j] = aa*Mr1[j] - am1*m1[j];
      m2[j] = aa*Mr2[j] - am1*m2[j];
      m3[j] = aa*Mr3[j] - am1*m3[j];
    }
    // newY = aa*Y - am1*(Y*M)  (Y-tile from regs)
    float y0[12], y1[12], y2[12], y3[12];
    zero12(y0); zero12(y1); zero12(y2); zero12(y3);
    mmtile4(&Lb[r0*24], &Lb[r1*24], &Lb[r2*24], &Lb[r3*24], La + c0,
            y0, y1, y2, y3);
#pragma unroll
    for (int j = 0; j < 12; ++j) {
      y0[j] = aa*Yr0[j] - am1*y0[j];
      y1[j] = aa*Yr1[j] - am1*y1[j];
      y2[j] = aa*Yr2[j] - am1*y2[j];
      y3[j] = aa*Yr3[j] - am1*y3[j];
    }
    __syncthreads();                              // La(M)/Lb(Y) reads done
    st12(&Lb[r0*24 + c0], m0); st12(&Lb[r1*24 + c0], m1);
    st12(&Lb[r2*24 + c0], m2); st12(&Lb[r3*24 + c0], m3);  // Lb = MT
    __syncthreads();
    // newM = aa*MT - am1*(MT*M)  (MT-tile from regs)
    float q0[12], q1[12], q2[12], q3[12];
    zero12(q0); zero12(q1); zero12(q2); zero12(q3);
    mmtile4(&Lb[r0*24], &Lb[r1*24], &Lb[r2*24], &Lb[r3*24], La + c0,
            q0, q1, q2, q3);
#pragma unroll
    for (int j = 0; j < 12; ++j) {
      Mr0[j] = aa*m0[j] - am1*q0[j];
      Mr1[j] = aa*m1[j] - am1*q1[j];
      Mr2[j] = aa*m2[j] - am1*q2[j];
      Mr3[j] = aa*m3[j] - am1*q3[j];
      Yr0[j] = y0[j]; Yr1[j] = y1[j]; Yr2[j] = y2[j]; Yr3[j] = y3[j];
    }
    __syncthreads();                              // Lb(MT)/La(M) reads done
    st12(&Lb[r0*24 + c0], Yr0); st12(&Lb[r1*24 + c0], Yr1);
    st12(&Lb[r2*24 + c0], Yr2); st12(&Lb[r3*24 + c0], Yr3); // Lb = newY
    st12(&La[r0*24 + c0], Mr0); st12(&La[r1*24 + c0], Mr1);
    st12(&La[r2*24 + c0], Mr2); st12(&La[r3*24 + c0], Mr3); // La = newM
    __syncthreads();
  }

  // ---- iter 8 (a=1.5): final Y = 1.5*Y - 0.5*(Y*M)   (Y-tile from regs)
  {
    float y0[12], y1[12], y2[12], y3[12];
    zero12(y0); zero12(y1); zero12(y2); zero12(y3);
    mmtile4(&Lb[r0*24], &Lb[r1*24], &Lb[r2*24], &Lb[r3*24], La + c0,
            y0, y1, y2, y3);
#pragma unroll
    for (int j = 0; j < 12; ++j) {
      y0[j] = 1.5f*Yr0[j] - 0.5f*y0[j];
      y1[j] = 1.5f*Yr1[j] - 0.5f*y1[j];
      y2[j] = 1.5f*Yr2[j] - 0.5f*y2[j];
      y3[j] = 1.5f*Yr3[j] - 0.5f*y3[j];
    }
    st12(io + mat*576 + r0*24 + c0, y0);
    st12(io + mat*576 + r1*24 + c0, y1);
    st12(io + mat*576 + r2*24 + c0, y2);
    st12(io + mat*576 + r3*24 + c0, y3);
  }
}

// ---------- host: Chebyshev interpolation -> monomial coefficients in u ----------
static void chebfit_host(double lo, double hi, int D, int islog, float* out) {
  const int N = 200;
  double a[32];
  for (int k = 0; k < 32; ++k) a[k] = 0.0;
  for (int i = 0; i < N; ++i) {
    double th = M_PI * (i + 0.5) / N;
    double u = cos(th);
    double xx = 0.5 * ((hi - lo) * u + (hi + lo));
    double f = islog ? log(xx) : exp(xx);
    for (int k = 0; k <= D; ++k) a[k] += f * cos(k * th);
  }
  for (int k = 0; k <= D; ++k) a[k] *= 2.0 / N;
  a[0] *= 0.5;
  double b[32], tp[32], tc[32], tn[32];
  for (int m = 0; m < 32; ++m) { b[m] = 0; tp[m] = 0; tc[m] = 0; tn[m] = 0; }
  tp[0] = 1.0; b[0] += a[0];
  tc[1] = 1.0; if (D >= 1) b[1] += a[1];
  for (int k = 2; k <= D; ++k) {
    for (int m = 0; m < 32; ++m) tn[m] = -tp[m];
    for (int m = 1; m < 32; ++m) tn[m] += 2.0 * tc[m-1];
    for (int m = 0; m <= k; ++m) b[m] += a[k] * tn[m];
    for (int m = 0; m < 32; ++m) { tp[m] = tc[m]; tc[m] = tn[m]; }
  }
  for (int m = 0; m < 32; ++m) out[m] = (float)b[m];
  out[30] = (float)(2.0 / (hi - lo));          // 1/d
  out[31] = (float)((hi + lo) / (hi - lo));    // c/d
}

extern "C" void kernel_launch(void* const* d_in, const int* in_sizes, int n_in,
                              void* d_out, int out_size, void* d_ws, size_t ws_size,
                              hipStream_t stream) {
  const float* x = (const float*)d_in[0];
  const float* A = (const float*)d_in[1];
  const float* W = (const float*)d_in[2];
  float* out = (float*)d_out;

  Coefs cl, ce;
  chebfit_host(0.47, 7.9, 23, 1, cl.c);   // log on the SPD input spectrum
  chebfit_host(-1.8, 3.9, 11, 0, ce.c);   // exp on the aggregated tangent spectrum

  k_logm <<<NMATS/MATS, BLK, 0, stream>>>(x, out, cl);
  k_agg  <<<NGROUPS,   256, 0, stream>>>(A, out);
  k_expm <<<NMATS/MATS, BLK, 0, stream>>>(out, ce);
  k_csqrt<<<NMATS/MATS4, BLK, 0, stream>>>(out, W);
}